// Round 7
// baseline (308.044 us; speedup 1.0000x reference)
//
#include <hip/hip_runtime.h>
#include <hip/hip_bf16.h>

#define NN 512
#define NI 64
#define NJ 16
#define DD 256
#define HI 64
#define HO 64

typedef unsigned int  u32;
typedef unsigned short u16;

typedef __attribute__((ext_vector_type(8))) short bf16x8;
typedef __attribute__((ext_vector_type(4))) float f32x4;

__device__ __forceinline__ float gelu_exact(float x){
    return 0.5f * x * (1.0f + erff(x * 0.7071067811865476f));
}
__device__ __forceinline__ float sigm(float x){
    return 1.0f / (1.0f + __expf(-x));
}
__device__ __forceinline__ float us2f(u16 u){
    union { u32 ui; float f; } cv; cv.ui = ((u32)u) << 16; return cv.f;
}
__device__ __forceinline__ float bflo(u32 x){
    union { u32 u; float f; } c; c.u = x << 16; return c.f;
}
__device__ __forceinline__ float bfhi(u32 x){
    union { u32 u; float f; } c; c.u = x & 0xffff0000u; return c.f;
}
__device__ __forceinline__ u16 f2us(float f){
    union { float f; u32 u; } cv; cv.f = f;
    u32 r = cv.u + 0x7FFFu + ((cv.u >> 16) & 1u);   // RNE
    return (u16)(r >> 16);
}
__device__ __forceinline__ float dot8(uint4 q, const float* v){
    return bflo(q.x) * v[0] + bfhi(q.x) * v[1]
         + bflo(q.y) * v[2] + bfhi(q.y) * v[3]
         + bflo(q.z) * v[4] + bfhi(q.z) * v[5]
         + bflo(q.w) * v[6] + bfhi(q.w) * v[7];
}

// ------------- prep: small weights -> bf16 (fe1W transposed) -------------
__global__ __launch_bounds__(256) void k_prep_small(
    const float* __restrict__ fn1W, const float* __restrict__ fe2W,
    const float* __restrict__ fn2W, const float* __restrict__ fe1W,
    u16* __restrict__ fn1wb, u16* __restrict__ wAb,
    u16* __restrict__ wBb, u16* __restrict__ wCtb)
{
    const int t = threadIdx.x;
    #pragma unroll
    for (int u = 0; u < 16; ++u){
        int idx = t + u * 256;
        fn1wb[idx] = f2us(fn1W[idx]);
        wAb[idx]   = f2us(fe2W[idx]);
        wBb[idx]   = f2us(fn2W[idx]);
        int n = idx >> 6, h = idx & 63;
        wCtb[idx]  = f2us(fe1W[h * 64 + n]);   // wCt[n][h] = fe1W[h][n]
    }
}

// ---------------- Kernel A: xc = gelu(x @ Wcap + Bcap)  --  MFMA ----------------
// grid (8 nc, 64 i), block 256 = 4 waves (16-row strips). WcapT staged once
// per block as XOR-swizzled bf16 [h][k] (b128 frag reads); A-frags from global
// x with in-reg RNE bf16 convert. One barrier total.
__global__ __launch_bounds__(256) void k_xc(const float* __restrict__ x,
    const float* __restrict__ Wcap, const float* __restrict__ Bcap,
    u16* __restrict__ xcb)
{
    __shared__ u16 wt_l[16384];        // 32 KB: WcapT [h][k], granule-swizzled
    __shared__ u16 strip[4][1024];     // 2 KB per-wave epilogue staging
    const int nc = blockIdx.x, i = blockIdx.y;
    const int n0 = nc * 64;
    const int t = threadIdx.x;
    const int w = t >> 6, l = t & 63;
    const int lr = l & 15, lg = l >> 4;

    // stage WcapT: lane h = t&63, k-group kg = t>>6; 32 passes x 2 k each
    {
        const float* wsrc = Wcap + (size_t)i * (DD * HI);
        const int h = t & 63, kg = t >> 6;
        #pragma unroll
        for (int p = 0; p < 32; ++p){
            const int k = (p * 4 + kg) * 2;
            u32 lo = f2us(wsrc[(size_t)k * HI + h]);
            u32 hi = f2us(wsrc[(size_t)(k + 1) * HI + h]);
            const int g = k >> 3;
            *(u32*)&wt_l[h * 256 + ((g ^ (h & 7)) << 3) + (k & 7)] = lo | (hi << 16);
        }
    }
    __syncthreads();

    // wave w computes rows [n0+16w, +16)
    const float* xrow = x + ((size_t)(n0 + 16 * w + lr) * NI + i) * DD;
    f32x4 acc[4] = {};
    #pragma unroll
    for (int ks = 0; ks < 8; ++ks){
        float4 f0 = *(const float4*)(xrow + ks * 32 + lg * 8);
        float4 f1 = *(const float4*)(xrow + ks * 32 + lg * 8 + 4);
        bf16x8 a;
        a[0] = (short)f2us(f0.x); a[1] = (short)f2us(f0.y);
        a[2] = (short)f2us(f0.z); a[3] = (short)f2us(f0.w);
        a[4] = (short)f2us(f1.x); a[5] = (short)f2us(f1.y);
        a[6] = (short)f2us(f1.z); a[7] = (short)f2us(f1.w);
        #pragma unroll
        for (int ht = 0; ht < 4; ++ht){
            const int h = ht * 16 + lr;
            bf16x8 b = *(const bf16x8*)&wt_l[h * 256 + (((ks * 4 + lg) ^ (lr & 7)) << 3)];
            acc[ht] = __builtin_amdgcn_mfma_f32_16x16x32_bf16(a, b, acc[ht], 0, 0, 0);
        }
    }

    // epilogue: bias + gelu -> swizzled strip -> coalesced store (intra-wave)
    u16* st = strip[w];
    #pragma unroll
    for (int ht = 0; ht < 4; ++ht){
        const int h = ht * 16 + lr, g = h >> 3;
        const float bc = Bcap[i * HI + h];
        #pragma unroll
        for (int r = 0; r < 4; ++r){
            const int m = lg * 4 + r;
            st[m * 64 + ((g ^ (m & 7)) << 3) + (h & 7)] = f2us(gelu_exact(acc[ht][r] + bc));
        }
    }
    {
        const int row = l >> 2, g0 = (l & 3) * 2;
        const size_t off = ((size_t)(n0 + 16 * w + row) * NI + i) * HI;
        #pragma unroll
        for (int gg = g0; gg < g0 + 2; ++gg){
            uint4 q = *(const uint4*)&st[row * 64 + ((gg ^ (row & 7)) << 3)];
            *(uint4*)(xcb + off + gg * 8) = q;
        }
    }
}

// ------- Kernel B: one block per (i,j); votes + fn_v (MFMA) + bij -------
// (unchanged from round 5; tiles stored pre-swizzled by i&7 at 16-B granules)
__global__ __launch_bounds__(256) void k_votes(
    const u16* __restrict__ xcb, const float* __restrict__ Wv,
    const float* __restrict__ Bv, const float* __restrict__ mask,
    const u16* __restrict__ fn1wb, const float* __restrict__ fn1b,
    const float* __restrict__ scoreW, const float* __restrict__ scoreb,
    u16* __restrict__ votes, u16* __restrict__ fnv, float* __restrict__ bij)
{
    __shared__ u16 vstrip[4][1024];
    __shared__ u16 fstrip[4][1024];
    const int i = blockIdx.x, j = blockIdx.y;
    const int t = threadIdx.x, w = t >> 6, l = t & 63;
    const int lr = l & 15, lg = l >> 4;
    const int isw = i & 7;

    bf16x8 wb0[4], wb1[4], nb0[4], nb1[4];
    const float* wvp = Wv + (size_t)(i * NJ + j) * 4096;
    float bv[4], f1b[4], swv[4];
    #pragma unroll
    for (int ht = 0; ht < 4; ++ht){
        const int h = ht * 16 + lr;
        #pragma unroll
        for (int e = 0; e < 8; ++e){
            wb0[ht][e] = (short)f2us(wvp[(lg * 8 + e) * 64 + h]);
            wb1[ht][e] = (short)f2us(wvp[(32 + lg * 8 + e) * 64 + h]);
        }
        const u16* q = fn1wb + h * 64 + lg * 8;
        nb0[ht] = *(const bf16x8*)q;
        nb1[ht] = *(const bf16x8*)(q + 32);
        bv[ht]  = Bv[(size_t)(i * NJ + j) * HO + h];
        f1b[ht] = fn1b[h];
        swv[ht] = scoreW[h];
    }
    const float sb = scoreb[0];
    u16* vst = vstrip[w];
    u16* fst = fstrip[w];

    for (int nc = 0; nc < 8; ++nc){
        const int n0 = nc * 64 + 16 * w;
        const u16* ar = xcb + ((size_t)(n0 + lr) * NI + i) * HI + lg * 8;
        bf16x8 a0 = *(const bf16x8*)ar;
        bf16x8 a1 = *(const bf16x8*)(ar + 32);
        float mk[4];
        #pragma unroll
        for (int r = 0; r < 4; ++r)
            mk[r] = mask[(size_t)(n0 + lg * 4 + r) * NI + i];

        float p[4] = {};
        #pragma unroll
        for (int ht = 0; ht < 4; ++ht){
            f32x4 c4 = {};
            c4 = __builtin_amdgcn_mfma_f32_16x16x32_bf16(a0, wb0[ht], c4, 0, 0, 0);
            c4 = __builtin_amdgcn_mfma_f32_16x16x32_bf16(a1, wb1[ht], c4, 0, 0, 0);
            const int h = ht * 16 + lr, gp = h >> 3;
            #pragma unroll
            for (int r = 0; r < 4; ++r){
                const int rs = lg * 4 + r;
                float val = (c4[r] + bv[ht]) * mk[r];
                p[r] += val * swv[ht];
                vst[rs * 64 + ((gp ^ (rs & 7)) << 3) + (h & 7)] = f2us(val);
            }
        }
        #pragma unroll
        for (int r = 0; r < 4; ++r){
            float s = p[r];
            s += __shfl_xor(s, 1); s += __shfl_xor(s, 2);
            s += __shfl_xor(s, 4); s += __shfl_xor(s, 8);
            if (lr == 0)
                bij[((size_t)(n0 + lg * 4 + r) * NJ + j) * NI + i] = s + sb;
        }

        const u16* va = vst + lr * 64;
        bf16x8 fa0 = *(const bf16x8*)(va + ((lg ^ (lr & 7)) << 3));
        bf16x8 fa1 = *(const bf16x8*)(va + (((lg + 4) ^ (lr & 7)) << 3));
        #pragma unroll
        for (int ht = 0; ht < 4; ++ht){
            f32x4 c4 = {};
            c4 = __builtin_amdgcn_mfma_f32_16x16x32_bf16(fa0, nb0[ht], c4, 0, 0, 0);
            c4 = __builtin_amdgcn_mfma_f32_16x16x32_bf16(fa1, nb1[ht], c4, 0, 0, 0);
            const int h = ht * 16 + lr, gp = h >> 3;
            #pragma unroll
            for (int r = 0; r < 4; ++r){
                const int rs = lg * 4 + r;
                fst[rs * 64 + ((gp ^ (rs & 7)) << 3) + (h & 7)] = f2us(c4[r] + f1b[ht]);
            }
        }

        {
            const int row = l >> 2, g0 = (l & 3) * 2;
            const size_t off = (((size_t)(nc * 64 + 16 * w + row) * NJ + j) * NI + i) * HO;
            #pragma unroll
            for (int gg = g0; gg < g0 + 2; ++gg){
                uint4 qv = *(const uint4*)&vst[row * 64 + ((gg ^ (row & 7)) << 3)];
                *(uint4*)(votes + off + ((gg ^ isw) << 3)) = qv;
                uint4 qf = *(const uint4*)&fst[row * 64 + ((gg ^ (row & 7)) << 3)];
                *(uint4*)(fnv + off + ((gg ^ isw) << 3)) = qf;
            }
        }
    }
}

// ---------------- Kernel C: routing; ONE wave per (n,j), ZERO barriers ----------------
// Same structure as round 6; serial fp32 chains broken into parallel partials.
__global__ __launch_bounds__(256, 4) void k_route(
    const u16* __restrict__ votes, const u16* __restrict__ fnv,
    const float* __restrict__ bijg, const float* __restrict__ mask,
    const float* __restrict__ alphaW, const float* __restrict__ alphab,
    const u16* __restrict__ wAb, const float* __restrict__ fe2b,
    const u16* __restrict__ wBb, const float* __restrict__ fn2b,
    const u16* __restrict__ wCtb, const float* __restrict__ fe1b,
    const int* __restrict__ itersp, float* __restrict__ out)
{
    __shared__ u16  t_l[4][4096];                  // 8 KB tile per wave
    __shared__ float s_aij[4][64], s_vj[4][64], s_g[4][64], s_w[4][64], s_u[4][64];

    const int t = threadIdx.x;
    const int wid = t >> 6;
    const int l = t & 63;
    const int pair = blockIdx.x * 4 + wid;
    const int n = pair >> 4, j = pair & 15;
    const size_t base = ((size_t)n * NJ + j) * (size_t)(NI * HO);

    u16*   tile = t_l[wid];
    float* aij  = s_aij[wid];
    float* svj  = s_vj[wid];
    float* sg   = s_g[wid];
    float* sw_  = s_w[wid];
    float* su   = s_u[wid];

    // ---- fnv -> LDS -> dr_f (row regs) ----
    uint4 dr_f[8];
    {
        const uint4* src = (const uint4*)(fnv + base);
        uint4 tb[8];
        #pragma unroll
        for (int c = 0; c < 8; ++c) tb[c] = src[c * 64 + l];
        #pragma unroll
        for (int c = 0; c < 8; ++c) *(uint4*)&tile[(c * 64 + l) * 8] = tb[c];
        #pragma unroll
        for (int c = 0; c < 8; ++c)
            dr_f[c] = *(const uint4*)&tile[l * 64 + ((c ^ (l & 7)) << 3)];
    }
    // ---- votes -> LDS (resident for nv loop + E-phase row reads) ----
    {
        const uint4* src = (const uint4*)(votes + base);
        uint4 tb[8];
        #pragma unroll
        for (int c = 0; c < 8; ++c) tb[c] = src[c * 64 + l];
        #pragma unroll
        for (int c = 0; c < 8; ++c) *(uint4*)&tile[(c * 64 + l) * 8] = tb[c];
    }

    const float mki  = mask[(size_t)n * NI + l];
    const float atti = (mki == 0.f) ? -3.0e38f : 0.f;

    {   // softmax over i (in-wave)
        float s = bijg[((size_t)n * NJ + j) * NI + l] * mki + atti;
        float mx = s;
        #pragma unroll
        for (int off = 32; off; off >>= 1) mx = fmaxf(mx, __shfl_xor(mx, off));
        float pe = __expf(s - mx);
        float sm = pe;
        #pragma unroll
        for (int off = 32; off; off >>= 1) sm += __shfl_xor(sm, off);
        aij[l] = pe / sm;
    }

    const int iters = itersp[0];
    float vj = 0.f;                                // lane l owns vj[h=l]
    for (int it = 0; it < iters; ++it){
        // nv[h=l] = sum_i aij[i]*votes[i][h] -- 4 parallel chains
        const int gsh = (l >> 3) << 3;
        const int lo7 = l & 7;
        float ac0 = 0.f, ac1 = 0.f, ac2 = 0.f, ac3 = 0.f;
        #pragma unroll
        for (int ii = 0; ii < 16; ++ii){
            const int sw = (gsh ^ ((ii & 7) << 3)) + lo7;
            ac0 += aij[ii]      * us2f(tile[ ii       * 64 + sw]);
            ac1 += aij[ii + 16] * us2f(tile[(ii + 16) * 64 + sw]);
            ac2 += aij[ii + 32] * us2f(tile[(ii + 32) * 64 + sw]);
            ac3 += aij[ii + 48] * us2f(tile[(ii + 48) * 64 + sw]);
        }
        float nv = gelu_exact((ac0 + ac1) + (ac2 + ac3));
        if (it == 0) vj = nv;
        else {
            float dv = nv * alphaW[l];
            #pragma unroll
            for (int off = 32; off; off >>= 1) dv += __shfl_xor(dv, off);
            float alpha = sigm(dv + alphab[0]);
            vj = alpha * nv + (1.f - alpha) * vj;
        }
        if (it == iters - 1) break;
        svj[l] = vj;

        // g = fe2(vj), w = fn2(vj) -- 4 interleaved chains
        const uint4* wa = (const uint4*)(wAb + l * 64);
        const uint4* wb = (const uint4*)(wBb + l * 64);
        float ga0 = 0.f, ga1 = 0.f, wc0 = 0.f, wc1 = 0.f;
        #pragma unroll
        for (int c = 0; c < 4; ++c){
            ga0 += dot8(wa[c],     &svj[c * 8]);
            wc0 += dot8(wb[c],     &svj[c * 8]);
            ga1 += dot8(wa[c + 4], &svj[(c + 4) * 8]);
            wc1 += dot8(wb[c + 4], &svj[(c + 4) * 8]);
        }
        float g = ga0 + ga1 + fe2b[l];
        sg[l]  = g;
        sw_[l] = wc0 + wc1 + fn2b[l];

        // u = fe1W^T g ; scal = fe1b . g
        const uint4* wc = (const uint4*)(wCtb + l * 64);
        float ua0 = 0.f, ua1 = 0.f;
        #pragma unroll
        for (int c = 0; c < 4; ++c){
            ua0 += dot8(wc[c],     &sg[c * 8]);
            ua1 += dot8(wc[c + 4], &sg[(c + 4) * 8]);
        }
        su[l] = ua0 + ua1;
        float cv = fe1b[l] * g;
        #pragma unroll
        for (int off = 32; off; off >>= 1) cv += __shfl_xor(cv, off);

        // M[i=l] = -sum_h |fnv[i][h] - w[h]| -- 2 chains
        float m0 = 0.f, m1 = 0.f;
        #pragma unroll
        for (int c = 0; c < 4; ++c){
            uint4 q = dr_f[c];
            const float* wp = &sw_[c * 8];
            m0 += fabsf(bflo(q.x) - wp[0]) + fabsf(bfhi(q.x) - wp[1])
                + fabsf(bflo(q.y) - wp[2]) + fabsf(bfhi(q.y) - wp[3])
                + fabsf(bflo(q.z) - wp[4]) + fabsf(bfhi(q.z) - wp[5])
                + fabsf(bflo(q.w) - wp[6]) + fabsf(bfhi(q.w) - wp[7]);
            uint4 q2 = dr_f[c + 4];
            const float* wp2 = &sw_[(c + 4) * 8];
            m1 += fabsf(bflo(q2.x) - wp2[0]) + fabsf(bfhi(q2.x) - wp2[1])
                + fabsf(bflo(q2.y) - wp2[2]) + fabsf(bfhi(q2.y) - wp2[3])
                + fabsf(bflo(q2.z) - wp2[4]) + fabsf(bfhi(q2.z) - wp2[5])
                + fabsf(bflo(q2.w) - wp2[6]) + fabsf(bfhi(q2.w) - wp2[7]);
        }

        // E[i=l] = votes[i].u + scal -- 2 chains (rows from LDS)
        float e0 = 0.f, e1 = 0.f;
        #pragma unroll
        for (int c = 0; c < 4; ++c){
            uint4 q  = *(const uint4*)&tile[l * 64 + ((c ^ (l & 7)) << 3)];
            uint4 q2 = *(const uint4*)&tile[l * 64 + (((c + 4) ^ (l & 7)) << 3)];
            e0 += dot8(q,  &su[c * 8]);
            e1 += dot8(q2, &su[(c + 4) * 8]);
        }
        aij[l] = tanhf(cv + e0 + e1) * sigm(-(m0 + m1) * mki + atti);
    }

    out[((size_t)n * NJ + j) * HO + l] = vj;
}

extern "C" void kernel_launch(void* const* d_in, const int* in_sizes, int n_in,
                              void* d_out, int out_size, void* d_ws, size_t ws_size,
                              hipStream_t stream)
{
    (void)in_sizes; (void)n_in; (void)out_size; (void)ws_size;
    const float* x      = (const float*)d_in[0];
    const float* mask   = (const float*)d_in[1];
    const float* Wcap   = (const float*)d_in[2];
    const float* Bcap   = (const float*)d_in[3];
    const float* Wv     = (const float*)d_in[4];
    const float* Bv     = (const float*)d_in[5];
    const float* scoreW = (const float*)d_in[6];
    const float* scoreb = (const float*)d_in[7];
    const float* alphaW = (const float*)d_in[8];
    const float* alphab = (const float*)d_in[9];
    const float* fe1W   = (const float*)d_in[10];
    const float* fe1b   = (const float*)d_in[11];
    const float* fe2W   = (const float*)d_in[12];
    const float* fe2b   = (const float*)d_in[13];
    const float* fn1W   = (const float*)d_in[14];
    const float* fn1b   = (const float*)d_in[15];
    const float* fn2W   = (const float*)d_in[16];
    const float* fn2b   = (const float*)d_in[17];
    const int*   itersp = (const int*)d_in[18];
    float* out = (float*)d_out;

    char* ws = (char*)d_ws;
    u16*   xcb   = (u16*)ws;                      //   4,194,304 B
    u16*   vts   = (u16*)(ws + 4194304);          //  67,108,864 B
    u16*   fnvp  = (u16*)(ws + 71303168);         //  67,108,864 B
    float* bij   = (float*)(ws + 138412032);      //   2,097,152 B
    u16*   fn1wb = (u16*)(ws + 140509184);        //       8,192 B
    u16*   wAb   = (u16*)(ws + 140517376);        //       8,192 B
    u16*   wBb   = (u16*)(ws + 140525568);        //       8,192 B
    u16*   wCtb  = (u16*)(ws + 140533760);        //       8,192 B  (~140.5 MB)

    k_prep_small<<<1, 256, 0, stream>>>(fn1W, fe2W, fn2W, fe1W, fn1wb, wAb, wBb, wCtb);
    k_xc        <<<dim3(8, 64), 256, 0, stream>>>(x, Wcap, Bcap, xcb);
    k_votes     <<<dim3(64, 16), 256, 0, stream>>>(xcb, Wv, Bv, mask, fn1wb, fn1b,
                                                   scoreW, scoreb, vts, fnvp, bij);
    k_route     <<<2048, 256, 0, stream>>>(vts, fnvp, bij, mask, alphaW, alphab,
                                           wAb, fe2b, wBb, fn2b, wCtb, fe1b,
                                           itersp, out);
}

// Round 8
// 169.672 us; speedup vs baseline: 1.8155x; 1.8155x over previous
//
#include <hip/hip_runtime.h>
#include <hip/hip_bf16.h>

#define NN 512
#define NI 64
#define NJ 16
#define DD 256
#define HI 64
#define HO 64

typedef unsigned int  u32;
typedef unsigned short u16;

typedef __attribute__((ext_vector_type(8))) short bf16x8;
typedef __attribute__((ext_vector_type(4))) float f32x4;

__device__ __forceinline__ float gelu_exact(float x){
    return 0.5f * x * (1.0f + erff(x * 0.7071067811865476f));
}
__device__ __forceinline__ float sigm(float x){
    return 1.0f / (1.0f + __expf(-x));
}
__device__ __forceinline__ float us2f(u16 u){
    union { u32 ui; float f; } cv; cv.ui = ((u32)u) << 16; return cv.f;
}
__device__ __forceinline__ float bflo(u32 x){
    union { u32 u; float f; } c; c.u = x << 16; return c.f;
}
__device__ __forceinline__ float bfhi(u32 x){
    union { u32 u; float f; } c; c.u = x & 0xffff0000u; return c.f;
}
__device__ __forceinline__ u16 f2us(float f){
    union { float f; u32 u; } cv; cv.f = f;
    u32 r = cv.u + 0x7FFFu + ((cv.u >> 16) & 1u);   // RNE
    return (u16)(r >> 16);
}
__device__ __forceinline__ float dot8(uint4 q, const float* v){
    return bflo(q.x) * v[0] + bfhi(q.x) * v[1]
         + bflo(q.y) * v[2] + bfhi(q.y) * v[3]
         + bflo(q.z) * v[4] + bfhi(q.z) * v[5]
         + bflo(q.w) * v[6] + bfhi(q.w) * v[7];
}

// ------------- prep: small weights -> bf16 (fe1W transposed) -------------
__global__ __launch_bounds__(256) void k_prep_small(
    const float* __restrict__ fn1W, const float* __restrict__ fe2W,
    const float* __restrict__ fn2W, const float* __restrict__ fe1W,
    u16* __restrict__ fn1wb, u16* __restrict__ wAb,
    u16* __restrict__ wBb, u16* __restrict__ wCtb)
{
    const int t = threadIdx.x;
    #pragma unroll
    for (int u = 0; u < 16; ++u){
        int idx = t + u * 256;
        fn1wb[idx] = f2us(fn1W[idx]);
        wAb[idx]   = f2us(fe2W[idx]);
        wBb[idx]   = f2us(fn2W[idx]);
        int n = idx >> 6, h = idx & 63;
        wCtb[idx]  = f2us(fe1W[h * 64 + n]);   // wCt[n][h] = fe1W[h][n]
    }
}

// ---------------- Kernel A: xc = gelu(x @ Wcap + Bcap)  --  MFMA ----------------
__global__ __launch_bounds__(256) void k_xc(const float* __restrict__ x,
    const float* __restrict__ Wcap, const float* __restrict__ Bcap,
    u16* __restrict__ xcb)
{
    __shared__ u16 wt_l[16384];        // 32 KB: WcapT [h][k], granule-swizzled
    __shared__ u16 strip[4][1024];     // 2 KB per-wave epilogue staging
    const int nc = blockIdx.x, i = blockIdx.y;
    const int n0 = nc * 64;
    const int t = threadIdx.x;
    const int w = t >> 6, l = t & 63;
    const int lr = l & 15, lg = l >> 4;

    // stage WcapT: lane h = t&63, k-group kg = t>>6; 32 passes x 2 k each
    {
        const float* wsrc = Wcap + (size_t)i * (DD * HI);
        const int h = t & 63, kg = t >> 6;
        #pragma unroll
        for (int p = 0; p < 32; ++p){
            const int k = (p * 4 + kg) * 2;
            u32 lo = f2us(wsrc[(size_t)k * HI + h]);
            u32 hi = f2us(wsrc[(size_t)(k + 1) * HI + h]);
            const int g = k >> 3;
            *(u32*)&wt_l[h * 256 + ((g ^ (h & 7)) << 3) + (k & 7)] = lo | (hi << 16);
        }
    }
    __syncthreads();

    // wave w computes rows [n0+16w, +16)
    const float* xrow = x + ((size_t)(n0 + 16 * w + lr) * NI + i) * DD;
    f32x4 acc[4] = {};
    #pragma unroll
    for (int ks = 0; ks < 8; ++ks){
        float4 f0 = *(const float4*)(xrow + ks * 32 + lg * 8);
        float4 f1 = *(const float4*)(xrow + ks * 32 + lg * 8 + 4);
        bf16x8 a;
        a[0] = (short)f2us(f0.x); a[1] = (short)f2us(f0.y);
        a[2] = (short)f2us(f0.z); a[3] = (short)f2us(f0.w);
        a[4] = (short)f2us(f1.x); a[5] = (short)f2us(f1.y);
        a[6] = (short)f2us(f1.z); a[7] = (short)f2us(f1.w);
        #pragma unroll
        for (int ht = 0; ht < 4; ++ht){
            const int h = ht * 16 + lr;
            bf16x8 b = *(const bf16x8*)&wt_l[h * 256 + (((ks * 4 + lg) ^ (lr & 7)) << 3)];
            acc[ht] = __builtin_amdgcn_mfma_f32_16x16x32_bf16(a, b, acc[ht], 0, 0, 0);
        }
    }

    // epilogue: bias + gelu -> swizzled strip -> coalesced store (intra-wave)
    u16* st = strip[w];
    #pragma unroll
    for (int ht = 0; ht < 4; ++ht){
        const int h = ht * 16 + lr, g = h >> 3;
        const float bc = Bcap[i * HI + h];
        #pragma unroll
        for (int r = 0; r < 4; ++r){
            const int m = lg * 4 + r;
            st[m * 64 + ((g ^ (m & 7)) << 3) + (h & 7)] = f2us(gelu_exact(acc[ht][r] + bc));
        }
    }
    {
        const int row = l >> 2, g0 = (l & 3) * 2;
        const size_t off = ((size_t)(n0 + 16 * w + row) * NI + i) * HI;
        #pragma unroll
        for (int gg = g0; gg < g0 + 2; ++gg){
            uint4 q = *(const uint4*)&st[row * 64 + ((gg ^ (row & 7)) << 3)];
            *(uint4*)(xcb + off + gg * 8) = q;
        }
    }
}

// ------- Kernel B: one block per (i,j); votes + fn_v (MFMA) + bij -------
__global__ __launch_bounds__(256) void k_votes(
    const u16* __restrict__ xcb, const float* __restrict__ Wv,
    const float* __restrict__ Bv, const float* __restrict__ mask,
    const u16* __restrict__ fn1wb, const float* __restrict__ fn1b,
    const float* __restrict__ scoreW, const float* __restrict__ scoreb,
    u16* __restrict__ votes, u16* __restrict__ fnv, float* __restrict__ bij)
{
    __shared__ u16 vstrip[4][1024];
    __shared__ u16 fstrip[4][1024];
    const int i = blockIdx.x, j = blockIdx.y;
    const int t = threadIdx.x, w = t >> 6, l = t & 63;
    const int lr = l & 15, lg = l >> 4;
    const int isw = i & 7;

    bf16x8 wb0[4], wb1[4], nb0[4], nb1[4];
    const float* wvp = Wv + (size_t)(i * NJ + j) * 4096;
    float bv[4], f1b[4], swv[4];
    #pragma unroll
    for (int ht = 0; ht < 4; ++ht){
        const int h = ht * 16 + lr;
        #pragma unroll
        for (int e = 0; e < 8; ++e){
            wb0[ht][e] = (short)f2us(wvp[(lg * 8 + e) * 64 + h]);
            wb1[ht][e] = (short)f2us(wvp[(32 + lg * 8 + e) * 64 + h]);
        }
        const u16* q = fn1wb + h * 64 + lg * 8;
        nb0[ht] = *(const bf16x8*)q;
        nb1[ht] = *(const bf16x8*)(q + 32);
        bv[ht]  = Bv[(size_t)(i * NJ + j) * HO + h];
        f1b[ht] = fn1b[h];
        swv[ht] = scoreW[h];
    }
    const float sb = scoreb[0];
    u16* vst = vstrip[w];
    u16* fst = fstrip[w];

    for (int nc = 0; nc < 8; ++nc){
        const int n0 = nc * 64 + 16 * w;
        const u16* ar = xcb + ((size_t)(n0 + lr) * NI + i) * HI + lg * 8;
        bf16x8 a0 = *(const bf16x8*)ar;
        bf16x8 a1 = *(const bf16x8*)(ar + 32);
        float mk[4];
        #pragma unroll
        for (int r = 0; r < 4; ++r)
            mk[r] = mask[(size_t)(n0 + lg * 4 + r) * NI + i];

        float p[4] = {};
        #pragma unroll
        for (int ht = 0; ht < 4; ++ht){
            f32x4 c4 = {};
            c4 = __builtin_amdgcn_mfma_f32_16x16x32_bf16(a0, wb0[ht], c4, 0, 0, 0);
            c4 = __builtin_amdgcn_mfma_f32_16x16x32_bf16(a1, wb1[ht], c4, 0, 0, 0);
            const int h = ht * 16 + lr, gp = h >> 3;
            #pragma unroll
            for (int r = 0; r < 4; ++r){
                const int rs = lg * 4 + r;
                float val = (c4[r] + bv[ht]) * mk[r];
                p[r] += val * swv[ht];
                vst[rs * 64 + ((gp ^ (rs & 7)) << 3) + (h & 7)] = f2us(val);
            }
        }
        #pragma unroll
        for (int r = 0; r < 4; ++r){
            float s = p[r];
            s += __shfl_xor(s, 1); s += __shfl_xor(s, 2);
            s += __shfl_xor(s, 4); s += __shfl_xor(s, 8);
            if (lr == 0)
                bij[((size_t)(n0 + lg * 4 + r) * NJ + j) * NI + i] = s + sb;
        }

        const u16* va = vst + lr * 64;
        bf16x8 fa0 = *(const bf16x8*)(va + ((lg ^ (lr & 7)) << 3));
        bf16x8 fa1 = *(const bf16x8*)(va + (((lg + 4) ^ (lr & 7)) << 3));
        #pragma unroll
        for (int ht = 0; ht < 4; ++ht){
            f32x4 c4 = {};
            c4 = __builtin_amdgcn_mfma_f32_16x16x32_bf16(fa0, nb0[ht], c4, 0, 0, 0);
            c4 = __builtin_amdgcn_mfma_f32_16x16x32_bf16(fa1, nb1[ht], c4, 0, 0, 0);
            const int h = ht * 16 + lr, gp = h >> 3;
            #pragma unroll
            for (int r = 0; r < 4; ++r){
                const int rs = lg * 4 + r;
                fst[rs * 64 + ((gp ^ (rs & 7)) << 3) + (h & 7)] = f2us(c4[r] + f1b[ht]);
            }
        }

        {
            const int row = l >> 2, g0 = (l & 3) * 2;
            const size_t off = (((size_t)(nc * 64 + 16 * w + row) * NJ + j) * NI + i) * HO;
            #pragma unroll
            for (int gg = g0; gg < g0 + 2; ++gg){
                uint4 qv = *(const uint4*)&vst[row * 64 + ((gg ^ (row & 7)) << 3)];
                *(uint4*)(votes + off + ((gg ^ isw) << 3)) = qv;
                uint4 qf = *(const uint4*)&fst[row * 64 + ((gg ^ (row & 7)) << 3)];
                *(uint4*)(fnv + off + ((gg ^ isw) << 3)) = qf;
            }
        }
    }
}

// ---------------- Kernel C: routing; ONE wave per (n,j), ZERO barriers ----------------
// NOTE: __launch_bounds__(256) ONLY — adding a min-waves arg (round 7) capped
// VGPRs at 64 and spilled dr_f/tb to scratch (374 MB fetch, 311 MB write, 3x slower).
__global__ __launch_bounds__(256) void k_route(
    const u16* __restrict__ votes, const u16* __restrict__ fnv,
    const float* __restrict__ bijg, const float* __restrict__ mask,
    const float* __restrict__ alphaW, const float* __restrict__ alphab,
    const u16* __restrict__ wAb, const float* __restrict__ fe2b,
    const u16* __restrict__ wBb, const float* __restrict__ fn2b,
    const u16* __restrict__ wCtb, const float* __restrict__ fe1b,
    const int* __restrict__ itersp, float* __restrict__ out)
{
    __shared__ u16  t_l[4][4096];                  // 8 KB tile per wave
    __shared__ float s_aij[4][64], s_vj[4][64], s_g[4][64], s_w[4][64], s_u[4][64];

    const int t = threadIdx.x;
    const int wid = t >> 6;
    const int l = t & 63;
    const int pair = blockIdx.x * 4 + wid;
    const int n = pair >> 4, j = pair & 15;
    const size_t base = ((size_t)n * NJ + j) * (size_t)(NI * HO);

    u16*   tile = t_l[wid];
    float* aij  = s_aij[wid];
    float* svj  = s_vj[wid];
    float* sg   = s_g[wid];
    float* sw_  = s_w[wid];
    float* su   = s_u[wid];

    // ---- fnv -> LDS -> dr_f (row regs) ----
    uint4 dr_f[8];
    {
        const uint4* src = (const uint4*)(fnv + base);
        uint4 tb[8];
        #pragma unroll
        for (int c = 0; c < 8; ++c) tb[c] = src[c * 64 + l];
        #pragma unroll
        for (int c = 0; c < 8; ++c) *(uint4*)&tile[(c * 64 + l) * 8] = tb[c];
        #pragma unroll
        for (int c = 0; c < 8; ++c)
            dr_f[c] = *(const uint4*)&tile[l * 64 + ((c ^ (l & 7)) << 3)];
    }
    // ---- votes -> LDS (resident for nv loop + E-phase row reads) ----
    {
        const uint4* src = (const uint4*)(votes + base);
        uint4 tb[8];
        #pragma unroll
        for (int c = 0; c < 8; ++c) tb[c] = src[c * 64 + l];
        #pragma unroll
        for (int c = 0; c < 8; ++c) *(uint4*)&tile[(c * 64 + l) * 8] = tb[c];
    }

    const float mki  = mask[(size_t)n * NI + l];
    const float atti = (mki == 0.f) ? -3.0e38f : 0.f;

    {   // softmax over i (in-wave)
        float s = bijg[((size_t)n * NJ + j) * NI + l] * mki + atti;
        float mx = s;
        #pragma unroll
        for (int off = 32; off; off >>= 1) mx = fmaxf(mx, __shfl_xor(mx, off));
        float pe = __expf(s - mx);
        float sm = pe;
        #pragma unroll
        for (int off = 32; off; off >>= 1) sm += __shfl_xor(sm, off);
        aij[l] = pe / sm;
    }

    const int iters = itersp[0];
    float vj = 0.f;                                // lane l owns vj[h=l]
    for (int it = 0; it < iters; ++it){
        // nv[h=l] = sum_i aij[i]*votes[i][h] -- 4 parallel chains
        const int gsh = (l >> 3) << 3;
        const int lo7 = l & 7;
        float ac0 = 0.f, ac1 = 0.f, ac2 = 0.f, ac3 = 0.f;
        #pragma unroll
        for (int ii = 0; ii < 16; ++ii){
            const int sw = (gsh ^ ((ii & 7) << 3)) + lo7;
            ac0 += aij[ii]      * us2f(tile[ ii       * 64 + sw]);
            ac1 += aij[ii + 16] * us2f(tile[(ii + 16) * 64 + sw]);
            ac2 += aij[ii + 32] * us2f(tile[(ii + 32) * 64 + sw]);
            ac3 += aij[ii + 48] * us2f(tile[(ii + 48) * 64 + sw]);
        }
        float nv = gelu_exact((ac0 + ac1) + (ac2 + ac3));
        if (it == 0) vj = nv;
        else {
            float dv = nv * alphaW[l];
            #pragma unroll
            for (int off = 32; off; off >>= 1) dv += __shfl_xor(dv, off);
            float alpha = sigm(dv + alphab[0]);
            vj = alpha * nv + (1.f - alpha) * vj;
        }
        if (it == iters - 1) break;
        svj[l] = vj;

        // g = fe2(vj), w = fn2(vj) -- 4 interleaved chains
        const uint4* wa = (const uint4*)(wAb + l * 64);
        const uint4* wb = (const uint4*)(wBb + l * 64);
        float ga0 = 0.f, ga1 = 0.f, wc0 = 0.f, wc1 = 0.f;
        #pragma unroll
        for (int c = 0; c < 4; ++c){
            ga0 += dot8(wa[c],     &svj[c * 8]);
            wc0 += dot8(wb[c],     &svj[c * 8]);
            ga1 += dot8(wa[c + 4], &svj[(c + 4) * 8]);
            wc1 += dot8(wb[c + 4], &svj[(c + 4) * 8]);
        }
        float g = ga0 + ga1 + fe2b[l];
        sg[l]  = g;
        sw_[l] = wc0 + wc1 + fn2b[l];

        // u = fe1W^T g ; scal = fe1b . g
        const uint4* wc = (const uint4*)(wCtb + l * 64);
        float ua0 = 0.f, ua1 = 0.f;
        #pragma unroll
        for (int c = 0; c < 4; ++c){
            ua0 += dot8(wc[c],     &sg[c * 8]);
            ua1 += dot8(wc[c + 4], &sg[(c + 4) * 8]);
        }
        su[l] = ua0 + ua1;
        float cv = fe1b[l] * g;
        #pragma unroll
        for (int off = 32; off; off >>= 1) cv += __shfl_xor(cv, off);

        // M[i=l] = -sum_h |fnv[i][h] - w[h]| -- 2 chains
        float m0 = 0.f, m1 = 0.f;
        #pragma unroll
        for (int c = 0; c < 4; ++c){
            uint4 q = dr_f[c];
            const float* wp = &sw_[c * 8];
            m0 += fabsf(bflo(q.x) - wp[0]) + fabsf(bfhi(q.x) - wp[1])
                + fabsf(bflo(q.y) - wp[2]) + fabsf(bfhi(q.y) - wp[3])
                + fabsf(bflo(q.z) - wp[4]) + fabsf(bfhi(q.z) - wp[5])
                + fabsf(bflo(q.w) - wp[6]) + fabsf(bfhi(q.w) - wp[7]);
            uint4 q2 = dr_f[c + 4];
            const float* wp2 = &sw_[(c + 4) * 8];
            m1 += fabsf(bflo(q2.x) - wp2[0]) + fabsf(bfhi(q2.x) - wp2[1])
                + fabsf(bflo(q2.y) - wp2[2]) + fabsf(bfhi(q2.y) - wp2[3])
                + fabsf(bflo(q2.z) - wp2[4]) + fabsf(bfhi(q2.z) - wp2[5])
                + fabsf(bflo(q2.w) - wp2[6]) + fabsf(bfhi(q2.w) - wp2[7]);
        }

        // E[i=l] = votes[i].u + scal -- 2 chains (rows from LDS)
        float e0 = 0.f, e1 = 0.f;
        #pragma unroll
        for (int c = 0; c < 4; ++c){
            uint4 q  = *(const uint4*)&tile[l * 64 + ((c ^ (l & 7)) << 3)];
            uint4 q2 = *(const uint4*)&tile[l * 64 + (((c + 4) ^ (l & 7)) << 3)];
            e0 += dot8(q,  &su[c * 8]);
            e1 += dot8(q2, &su[(c + 4) * 8]);
        }
        aij[l] = tanhf(cv + e0 + e1) * sigm(-(m0 + m1) * mki + atti);
    }

    out[((size_t)n * NJ + j) * HO + l] = vj;
}

extern "C" void kernel_launch(void* const* d_in, const int* in_sizes, int n_in,
                              void* d_out, int out_size, void* d_ws, size_t ws_size,
                              hipStream_t stream)
{
    (void)in_sizes; (void)n_in; (void)out_size; (void)ws_size;
    const float* x      = (const float*)d_in[0];
    const float* mask   = (const float*)d_in[1];
    const float* Wcap   = (const float*)d_in[2];
    const float* Bcap   = (const float*)d_in[3];
    const float* Wv     = (const float*)d_in[4];
    const float* Bv     = (const float*)d_in[5];
    const float* scoreW = (const float*)d_in[6];
    const float* scoreb = (const float*)d_in[7];
    const float* alphaW = (const float*)d_in[8];
    const float* alphab = (const float*)d_in[9];
    const float* fe1W   = (const float*)d_in[10];
    const float* fe1b   = (const float*)d_in[11];
    const float* fe2W   = (const float*)d_in[12];
    const float* fe2b   = (const float*)d_in[13];
    const float* fn1W   = (const float*)d_in[14];
    const float* fn1b   = (const float*)d_in[15];
    const float* fn2W   = (const float*)d_in[16];
    const float* fn2b   = (const float*)d_in[17];
    const int*   itersp = (const int*)d_in[18];
    float* out = (float*)d_out;

    char* ws = (char*)d_ws;
    u16*   xcb   = (u16*)ws;                      //   4,194,304 B
    u16*   vts   = (u16*)(ws + 4194304);          //  67,108,864 B
    u16*   fnvp  = (u16*)(ws + 71303168);         //  67,108,864 B
    float* bij   = (float*)(ws + 138412032);      //   2,097,152 B
    u16*   fn1wb = (u16*)(ws + 140509184);        //       8,192 B
    u16*   wAb   = (u16*)(ws + 140517376);        //       8,192 B
    u16*   wBb   = (u16*)(ws + 140525568);        //       8,192 B
    u16*   wCtb  = (u16*)(ws + 140533760);        //       8,192 B  (~140.5 MB)

    k_prep_small<<<1, 256, 0, stream>>>(fn1W, fe2W, fn2W, fe1W, fn1wb, wAb, wBb, wCtb);
    k_xc        <<<dim3(8, 64), 256, 0, stream>>>(x, Wcap, Bcap, xcb);
    k_votes     <<<dim3(64, 16), 256, 0, stream>>>(xcb, Wv, Bv, mask, fn1wb, fn1b,
                                                   scoreW, scoreb, vts, fnvp, bij);
    k_route     <<<2048, 256, 0, stream>>>(vts, fnvp, bij, mask, alphaW, alphab,
                                           wAb, fe2b, wBb, fn2b, wCtb, fe1b,
                                           itersp, out);
}

// Round 9
// 135.152 us; speedup vs baseline: 2.2792x; 1.2554x over previous
//
#include <hip/hip_runtime.h>
#include <hip/hip_bf16.h>

#define NN 512
#define NI 64
#define NJ 16
#define DD 256
#define HI 64
#define HO 64

typedef unsigned int  u32;
typedef unsigned short u16;

typedef __attribute__((ext_vector_type(8))) short bf16x8;
typedef __attribute__((ext_vector_type(4))) float f32x4;

__device__ __forceinline__ float gelu_exact(float x){
    return 0.5f * x * (1.0f + erff(x * 0.7071067811865476f));
}
__device__ __forceinline__ float sigm(float x){
    return 1.0f / (1.0f + __expf(-x));
}
__device__ __forceinline__ float us2f(u16 u){
    union { u32 ui; float f; } cv; cv.ui = ((u32)u) << 16; return cv.f;
}
__device__ __forceinline__ float bflo(u32 x){
    union { u32 u; float f; } c; c.u = x << 16; return c.f;
}
__device__ __forceinline__ float bfhi(u32 x){
    union { u32 u; float f; } c; c.u = x & 0xffff0000u; return c.f;
}
__device__ __forceinline__ u16 f2us(float f){
    union { float f; u32 u; } cv; cv.f = f;
    u32 r = cv.u + 0x7FFFu + ((cv.u >> 16) & 1u);   // RNE
    return (u16)(r >> 16);
}
__device__ __forceinline__ float dot8(uint4 q, const float* v){
    return bflo(q.x) * v[0] + bfhi(q.x) * v[1]
         + bflo(q.y) * v[2] + bfhi(q.y) * v[3]
         + bflo(q.z) * v[4] + bfhi(q.z) * v[5]
         + bflo(q.w) * v[6] + bfhi(q.w) * v[7];
}

// ------------- prep: small weights -> bf16 (fe1W transposed) -------------
__global__ __launch_bounds__(256) void k_prep_small(
    const float* __restrict__ fn1W, const float* __restrict__ fe2W,
    const float* __restrict__ fn2W, const float* __restrict__ fe1W,
    u16* __restrict__ fn1wb, u16* __restrict__ wAb,
    u16* __restrict__ wBb, u16* __restrict__ wCtb)
{
    const int t = threadIdx.x;
    #pragma unroll
    for (int u = 0; u < 16; ++u){
        int idx = t + u * 256;
        fn1wb[idx] = f2us(fn1W[idx]);
        wAb[idx]   = f2us(fe2W[idx]);
        wBb[idx]   = f2us(fn2W[idx]);
        int n = idx >> 6, h = idx & 63;
        wCtb[idx]  = f2us(fe1W[h * 64 + n]);   // wCt[n][h] = fe1W[h][n]
    }
}

// ---------------- Kernel A: xc = gelu(x @ Wcap + Bcap)  --  MFMA ----------------
__global__ __launch_bounds__(256) void k_xc(const float* __restrict__ x,
    const float* __restrict__ Wcap, const float* __restrict__ Bcap,
    u16* __restrict__ xcb)
{
    __shared__ u16 wt_l[16384];        // 32 KB: WcapT [h][k], granule-swizzled
    __shared__ u16 strip[4][1024];     // 2 KB per-wave epilogue staging
    const int nc = blockIdx.x, i = blockIdx.y;
    const int n0 = nc * 64;
    const int t = threadIdx.x;
    const int w = t >> 6, l = t & 63;
    const int lr = l & 15, lg = l >> 4;

    {
        const float* wsrc = Wcap + (size_t)i * (DD * HI);
        const int h = t & 63, kg = t >> 6;
        #pragma unroll
        for (int p = 0; p < 32; ++p){
            const int k = (p * 4 + kg) * 2;
            u32 lo = f2us(wsrc[(size_t)k * HI + h]);
            u32 hi = f2us(wsrc[(size_t)(k + 1) * HI + h]);
            const int g = k >> 3;
            *(u32*)&wt_l[h * 256 + ((g ^ (h & 7)) << 3) + (k & 7)] = lo | (hi << 16);
        }
    }
    __syncthreads();

    const float* xrow = x + ((size_t)(n0 + 16 * w + lr) * NI + i) * DD;
    f32x4 acc[4] = {};
    #pragma unroll
    for (int ks = 0; ks < 8; ++ks){
        float4 f0 = *(const float4*)(xrow + ks * 32 + lg * 8);
        float4 f1 = *(const float4*)(xrow + ks * 32 + lg * 8 + 4);
        bf16x8 a;
        a[0] = (short)f2us(f0.x); a[1] = (short)f2us(f0.y);
        a[2] = (short)f2us(f0.z); a[3] = (short)f2us(f0.w);
        a[4] = (short)f2us(f1.x); a[5] = (short)f2us(f1.y);
        a[6] = (short)f2us(f1.z); a[7] = (short)f2us(f1.w);
        #pragma unroll
        for (int ht = 0; ht < 4; ++ht){
            const int h = ht * 16 + lr;
            bf16x8 b = *(const bf16x8*)&wt_l[h * 256 + (((ks * 4 + lg) ^ (lr & 7)) << 3)];
            acc[ht] = __builtin_amdgcn_mfma_f32_16x16x32_bf16(a, b, acc[ht], 0, 0, 0);
        }
    }

    u16* st = strip[w];
    #pragma unroll
    for (int ht = 0; ht < 4; ++ht){
        const int h = ht * 16 + lr, g = h >> 3;
        const float bc = Bcap[i * HI + h];
        #pragma unroll
        for (int r = 0; r < 4; ++r){
            const int m = lg * 4 + r;
            st[m * 64 + ((g ^ (m & 7)) << 3) + (h & 7)] = f2us(gelu_exact(acc[ht][r] + bc));
        }
    }
    {
        const int row = l >> 2, g0 = (l & 3) * 2;
        const size_t off = ((size_t)(n0 + 16 * w + row) * NI + i) * HI;
        #pragma unroll
        for (int gg = g0; gg < g0 + 2; ++gg){
            uint4 q = *(const uint4*)&st[row * 64 + ((gg ^ (row & 7)) << 3)];
            *(uint4*)(xcb + off + gg * 8) = q;
        }
    }
}

// ------- Kernel B: one block per (i,j); votes (MFMA) + bij.  NO fnv. -------
__global__ __launch_bounds__(256) void k_votes(
    const u16* __restrict__ xcb, const float* __restrict__ Wv,
    const float* __restrict__ Bv, const float* __restrict__ mask,
    const float* __restrict__ scoreW, const float* __restrict__ scoreb,
    u16* __restrict__ votes, float* __restrict__ bij)
{
    __shared__ u16 vstrip[4][1024];
    const int i = blockIdx.x, j = blockIdx.y;
    const int t = threadIdx.x, w = t >> 6, l = t & 63;
    const int lr = l & 15, lg = l >> 4;
    const int isw = i & 7;

    bf16x8 wb0[4], wb1[4];
    const float* wvp = Wv + (size_t)(i * NJ + j) * 4096;
    float bv[4], swv[4];
    #pragma unroll
    for (int ht = 0; ht < 4; ++ht){
        const int h = ht * 16 + lr;
        #pragma unroll
        for (int e = 0; e < 8; ++e){
            wb0[ht][e] = (short)f2us(wvp[(lg * 8 + e) * 64 + h]);
            wb1[ht][e] = (short)f2us(wvp[(32 + lg * 8 + e) * 64 + h]);
        }
        bv[ht]  = Bv[(size_t)(i * NJ + j) * HO + h];
        swv[ht] = scoreW[h];
    }
    const float sb = scoreb[0];
    u16* vst = vstrip[w];

    for (int nc = 0; nc < 8; ++nc){
        const int n0 = nc * 64 + 16 * w;
        const u16* ar = xcb + ((size_t)(n0 + lr) * NI + i) * HI + lg * 8;
        bf16x8 a0 = *(const bf16x8*)ar;
        bf16x8 a1 = *(const bf16x8*)(ar + 32);
        float mk[4];
        #pragma unroll
        for (int r = 0; r < 4; ++r)
            mk[r] = mask[(size_t)(n0 + lg * 4 + r) * NI + i];

        float p[4] = {};
        #pragma unroll
        for (int ht = 0; ht < 4; ++ht){
            f32x4 c4 = {};
            c4 = __builtin_amdgcn_mfma_f32_16x16x32_bf16(a0, wb0[ht], c4, 0, 0, 0);
            c4 = __builtin_amdgcn_mfma_f32_16x16x32_bf16(a1, wb1[ht], c4, 0, 0, 0);
            const int h = ht * 16 + lr, gp = h >> 3;
            #pragma unroll
            for (int r = 0; r < 4; ++r){
                const int rs = lg * 4 + r;
                float val = (c4[r] + bv[ht]) * mk[r];
                p[r] += val * swv[ht];
                vst[rs * 64 + ((gp ^ (rs & 7)) << 3) + (h & 7)] = f2us(val);
            }
        }
        #pragma unroll
        for (int r = 0; r < 4; ++r){
            float s = p[r];
            s += __shfl_xor(s, 1); s += __shfl_xor(s, 2);
            s += __shfl_xor(s, 4); s += __shfl_xor(s, 8);
            if (lr == 0)
                bij[((size_t)(n0 + lg * 4 + r) * NJ + j) * NI + i] = s + sb;
        }

        {
            const int row = l >> 2, g0 = (l & 3) * 2;
            const size_t off = (((size_t)(nc * 64 + 16 * w + row) * NJ + j) * NI + i) * HO;
            #pragma unroll
            for (int gg = g0; gg < g0 + 2; ++gg){
                uint4 qv = *(const uint4*)&vst[row * 64 + ((gg ^ (row & 7)) << 3)];
                *(uint4*)(votes + off + ((gg ^ isw) << 3)) = qv;
            }
        }
    }
}

// ---------------- Kernel C: routing; ONE wave per (n,j), ZERO barriers ----------------
// Round-6 low-VGPR body; fnv eliminated — M recomputed per iteration via MFMA
// (A = fn1W frags from L1-hot global, B = votes rows from swizzled LDS tile;
// `if (lg == itile)` lands M[i] in lane i; validated in round 4).
// NOTE: plain __launch_bounds__(256) — a min-waves arg caps VGPR and spills (round 7).
__global__ __launch_bounds__(256) void k_route(
    const u16* __restrict__ votes, const float* __restrict__ bijg,
    const float* __restrict__ mask,
    const float* __restrict__ alphaW, const float* __restrict__ alphab,
    const u16* __restrict__ wAb, const float* __restrict__ fe2b,
    const u16* __restrict__ wBb, const float* __restrict__ fn2b,
    const u16* __restrict__ wCtb, const float* __restrict__ fe1b,
    const u16* __restrict__ fn1wb, const float* __restrict__ fn1b,
    const int* __restrict__ itersp, float* __restrict__ out)
{
    __shared__ u16  t_l[4][4096];                  // 8 KB votes tile per wave
    __shared__ float s_aij[4][64], s_vj[4][64], s_g[4][64], s_w[4][64], s_u[4][64];

    const int t = threadIdx.x;
    const int wid = t >> 6;
    const int l = t & 63;
    const int lr = l & 15, lg = l >> 4;
    const int pair = blockIdx.x * 4 + wid;
    const int n = pair >> 4, j = pair & 15;
    const size_t base = ((size_t)n * NJ + j) * (size_t)(NI * HO);

    u16*   tile = t_l[wid];
    float* aij  = s_aij[wid];
    float* svj  = s_vj[wid];
    float* sg   = s_g[wid];
    float* sw_  = s_w[wid];
    float* su   = s_u[wid];

    // ---- votes -> LDS (coalesced; resident for nv, M-recompute, E) ----
    {
        const uint4* src = (const uint4*)(votes + base);
        uint4 tb[8];
        #pragma unroll
        for (int c = 0; c < 8; ++c) tb[c] = src[c * 64 + l];
        #pragma unroll
        for (int c = 0; c < 8; ++c) *(uint4*)&tile[(c * 64 + l) * 8] = tb[c];
    }

    const float mki  = mask[(size_t)n * NI + l];
    const float atti = (mki == 0.f) ? -3.0e38f : 0.f;

    {   // softmax over i (in-wave)
        float s = bijg[((size_t)n * NJ + j) * NI + l] * mki + atti;
        float mx = s;
        #pragma unroll
        for (int off = 32; off; off >>= 1) mx = fmaxf(mx, __shfl_xor(mx, off));
        float pe = __expf(s - mx);
        float sm = pe;
        #pragma unroll
        for (int off = 32; off; off >>= 1) sm += __shfl_xor(sm, off);
        aij[l] = pe / sm;
    }

    const int iters = itersp[0];
    float vj = 0.f;                                // lane l owns vj[h=l]
    for (int it = 0; it < iters; ++it){
        // nv[h=l] = sum_i aij[i]*votes[i][h]  (swizzled column reads)
        float acc = 0.f;
        const int gsh = (l >> 3) << 3;
        #pragma unroll 8
        for (int i2 = 0; i2 < 64; ++i2){
            const int idx = i2 * 64 + (gsh ^ ((i2 & 7) << 3)) + (l & 7);
            acc += aij[i2] * us2f(tile[idx]);
        }
        float nv = gelu_exact(acc);
        if (it == 0) vj = nv;
        else {
            float dv = nv * alphaW[l];
            #pragma unroll
            for (int off = 32; off; off >>= 1) dv += __shfl_xor(dv, off);
            float alpha = sigm(dv + alphab[0]);
            vj = alpha * nv + (1.f - alpha) * vj;
        }
        if (it == iters - 1) break;
        svj[l] = vj;

        // g = fe2(vj), w = fn2(vj)
        const uint4* wa = (const uint4*)(wAb + l * 64);
        const uint4* wb = (const uint4*)(wBb + l * 64);
        float ga = 0.f, wacc = 0.f;
        #pragma unroll
        for (int c = 0; c < 8; ++c){
            ga   += dot8(wa[c], &svj[c * 8]);
            wacc += dot8(wb[c], &svj[c * 8]);
        }
        float g = ga + fe2b[l];
        sg[l]  = g;
        sw_[l] = wacc + fn2b[l];

        // u = fe1W^T g ; cv = fe1b . g
        const uint4* wc = (const uint4*)(wCtb + l * 64);
        float ua = 0.f;
        #pragma unroll
        for (int c = 0; c < 8; ++c) ua += dot8(wc[c], &sg[c * 8]);
        su[l] = ua;
        float cv = fe1b[l] * g;
        #pragma unroll
        for (int off = 32; off; off >>= 1) cv += __shfl_xor(cv, off);

        // M[i] via fn_v recompute (MFMA, B = swizzled tile rows) -- round-4 scheme
        float Mreg = 0.f;
        #pragma unroll
        for (int itile = 0; itile < 4; ++itile){
            const int row = itile * 16 + lr;       // i-row
            const u16* vr = &tile[row * 64];
            const int rs = (row & 7) << 3;
            bf16x8 vb0 = *(const bf16x8*)(vr + ((lg * 8) ^ rs));
            bf16x8 vb1 = *(const bf16x8*)(vr + ((32 + lg * 8) ^ rs));
            float mpart = 0.f;
            #pragma unroll
            for (int ht = 0; ht < 4; ++ht){
                const u16* ar = fn1wb + (ht * 16 + lr) * 64 + lg * 8;
                bf16x8 a0 = *(const bf16x8*)ar;
                bf16x8 a1 = *(const bf16x8*)(ar + 32);
                f32x4 c4 = {};
                c4 = __builtin_amdgcn_mfma_f32_16x16x32_bf16(a0, vb0, c4, 0, 0, 0);
                c4 = __builtin_amdgcn_mfma_f32_16x16x32_bf16(a1, vb1, c4, 0, 0, 0);
                #pragma unroll
                for (int r = 0; r < 4; ++r){
                    int hn = ht * 16 + lg * 4 + r;
                    mpart += fabsf(c4[r] + fn1b[hn] - sw_[hn]);
                }
            }
            mpart += __shfl_xor(mpart, 16);
            mpart += __shfl_xor(mpart, 32);
            if (lg == itile) Mreg = -mpart;        // lands in lane l = i
        }

        // E[i=l] = votes[i].u + cv  (row reads from LDS)
        float e = cv;
        #pragma unroll
        for (int c = 0; c < 8; ++c){
            uint4 q = *(const uint4*)&tile[l * 64 + ((c ^ (l & 7)) << 3)];
            e += dot8(q, &su[c * 8]);
        }
        aij[l] = tanhf(e) * sigm(Mreg * mki + atti);
    }

    out[((size_t)n * NJ + j) * HO + l] = vj;
}

extern "C" void kernel_launch(void* const* d_in, const int* in_sizes, int n_in,
                              void* d_out, int out_size, void* d_ws, size_t ws_size,
                              hipStream_t stream)
{
    (void)in_sizes; (void)n_in; (void)out_size; (void)ws_size;
    const float* x      = (const float*)d_in[0];
    const float* mask   = (const float*)d_in[1];
    const float* Wcap   = (const float*)d_in[2];
    const float* Bcap   = (const float*)d_in[3];
    const float* Wv     = (const float*)d_in[4];
    const float* Bv     = (const float*)d_in[5];
    const float* scoreW = (const float*)d_in[6];
    const float* scoreb = (const float*)d_in[7];
    const float* alphaW = (const float*)d_in[8];
    const float* alphab = (const float*)d_in[9];
    const float* fe1W   = (const float*)d_in[10];
    const float* fe1b   = (const float*)d_in[11];
    const float* fe2W   = (const float*)d_in[12];
    const float* fe2b   = (const float*)d_in[13];
    const float* fn1W   = (const float*)d_in[14];
    const float* fn1b   = (const float*)d_in[15];
    const float* fn2W   = (const float*)d_in[16];
    const float* fn2b   = (const float*)d_in[17];
    const int*   itersp = (const int*)d_in[18];
    float* out = (float*)d_out;

    char* ws = (char*)d_ws;
    u16*   xcb   = (u16*)ws;                      //   4,194,304 B
    u16*   vts   = (u16*)(ws + 4194304);          //  67,108,864 B
    float* bij   = (float*)(ws + 71303168);       //   2,097,152 B
    u16*   fn1wb = (u16*)(ws + 73400320);         //       8,192 B
    u16*   wAb   = (u16*)(ws + 73408512);         //       8,192 B
    u16*   wBb   = (u16*)(ws + 73416704);         //       8,192 B
    u16*   wCtb  = (u16*)(ws + 73424896);         //       8,192 B  (~73.4 MB)

    k_prep_small<<<1, 256, 0, stream>>>(fn1W, fe2W, fn2W, fe1W, fn1wb, wAb, wBb, wCtb);
    k_xc        <<<dim3(8, 64), 256, 0, stream>>>(x, Wcap, Bcap, xcb);
    k_votes     <<<dim3(64, 16), 256, 0, stream>>>(xcb, Wv, Bv, mask,
                                                   scoreW, scoreb, vts, bij);
    k_route     <<<2048, 256, 0, stream>>>(vts, bij, mask, alphaW, alphab,
                                           wAb, fe2b, wBb, fn2b, wCtb, fe1b,
                                           fn1wb, fn1b, itersp, out);
}

// Round 10
// 133.935 us; speedup vs baseline: 2.3000x; 1.0091x over previous
//
#include <hip/hip_runtime.h>
#include <hip/hip_bf16.h>

#define NN 512
#define NI 64
#define NJ 16
#define DD 256
#define HI 64
#define HO 64

typedef unsigned int  u32;
typedef unsigned short u16;

typedef _Float16 f16;
typedef __attribute__((ext_vector_type(2))) _Float16 f16x2;
typedef __attribute__((ext_vector_type(8))) _Float16 f16x8;
typedef __attribute__((ext_vector_type(4))) float f32x4;

__device__ __forceinline__ float gelu_exact(float x){
    return 0.5f * x * (1.0f + erff(x * 0.7071067811865476f));
}
__device__ __forceinline__ float sigm(float x){
    return 1.0f / (1.0f + __expf(-x));
}
__device__ __forceinline__ u16 f2h(float f){
    union { f16 h; u16 u; } c; c.h = (f16)f; return c.u;
}
__device__ __forceinline__ float h2f(u16 u){
    union { u16 u; f16 h; } c; c.u = u; return (float)c.h;
}
__device__ __forceinline__ f16x2 bch2(u32 x){
    union { u32 u; f16x2 h; } c; c.u = x; return c.h;
}
__device__ __forceinline__ f16x2 habs2(f16x2 a){
    union { f16x2 h; u32 u; } c; c.h = a; c.u &= 0x7FFF7FFFu; return c.h;
}
__device__ __forceinline__ float dot2f(u32 a, u32 b, float acc){
    return __builtin_amdgcn_fdot2(bch2(a), bch2(b), acc, false);
}
__device__ __forceinline__ float dot8h(uint4 q, uint4 v, float acc){
    acc = dot2f(q.x, v.x, acc);
    acc = dot2f(q.y, v.y, acc);
    acc = dot2f(q.z, v.z, acc);
    acc = dot2f(q.w, v.w, acc);
    return acc;
}

// ------------- prep: small weights -> f16 (fe1W transposed) -------------
__global__ __launch_bounds__(256) void k_prep_small(
    const float* __restrict__ fn1W, const float* __restrict__ fe2W,
    const float* __restrict__ fn2W, const float* __restrict__ fe1W,
    u16* __restrict__ fn1wh, u16* __restrict__ wAh,
    u16* __restrict__ wBh, u16* __restrict__ wCth)
{
    const int t = threadIdx.x;
    #pragma unroll
    for (int u = 0; u < 16; ++u){
        int idx = t + u * 256;
        fn1wh[idx] = f2h(fn1W[idx]);
        wAh[idx]   = f2h(fe2W[idx]);
        wBh[idx]   = f2h(fn2W[idx]);
        int n = idx >> 6, h = idx & 63;
        wCth[idx]  = f2h(fe1W[h * 64 + n]);   // wCt[n][h] = fe1W[h][n]
    }
}

// ---------------- Kernel A: xc = gelu(x @ Wcap + Bcap)  --  f16 MFMA ----------------
__global__ __launch_bounds__(256) void k_xc(const float* __restrict__ x,
    const float* __restrict__ Wcap, const float* __restrict__ Bcap,
    u16* __restrict__ xcb)
{
    __shared__ u16 wt_l[16384];        // 32 KB: WcapT [h][k] f16, granule-swizzled
    __shared__ u16 strip[4][1024];
    const int nc = blockIdx.x, i = blockIdx.y;
    const int n0 = nc * 64;
    const int t = threadIdx.x;
    const int w = t >> 6, l = t & 63;
    const int lr = l & 15, lg = l >> 4;

    {
        const float* wsrc = Wcap + (size_t)i * (DD * HI);
        const int h = t & 63, kg = t >> 6;
        #pragma unroll
        for (int p = 0; p < 32; ++p){
            const int k = (p * 4 + kg) * 2;
            u32 lo = f2h(wsrc[(size_t)k * HI + h]);
            u32 hi = f2h(wsrc[(size_t)(k + 1) * HI + h]);
            const int g = k >> 3;
            *(u32*)&wt_l[h * 256 + ((g ^ (h & 7)) << 3) + (k & 7)] = lo | (hi << 16);
        }
    }
    __syncthreads();

    const float* xrow = x + ((size_t)(n0 + 16 * w + lr) * NI + i) * DD;
    f32x4 acc[4] = {};
    #pragma unroll
    for (int ks = 0; ks < 8; ++ks){
        float4 f0 = *(const float4*)(xrow + ks * 32 + lg * 8);
        float4 f1 = *(const float4*)(xrow + ks * 32 + lg * 8 + 4);
        f16x8 a;
        a[0] = (f16)f0.x; a[1] = (f16)f0.y; a[2] = (f16)f0.z; a[3] = (f16)f0.w;
        a[4] = (f16)f1.x; a[5] = (f16)f1.y; a[6] = (f16)f1.z; a[7] = (f16)f1.w;
        #pragma unroll
        for (int ht = 0; ht < 4; ++ht){
            const int h = ht * 16 + lr;
            f16x8 b = *(const f16x8*)&wt_l[h * 256 + (((ks * 4 + lg) ^ (lr & 7)) << 3)];
            acc[ht] = __builtin_amdgcn_mfma_f32_16x16x32_f16(a, b, acc[ht], 0, 0, 0);
        }
    }

    u16* st = strip[w];
    #pragma unroll
    for (int ht = 0; ht < 4; ++ht){
        const int h = ht * 16 + lr, g = h >> 3;
        const float bc = Bcap[i * HI + h];
        #pragma unroll
        for (int r = 0; r < 4; ++r){
            const int m = lg * 4 + r;
            st[m * 64 + ((g ^ (m & 7)) << 3) + (h & 7)] = f2h(gelu_exact(acc[ht][r] + bc));
        }
    }
    {
        const int row = l >> 2, g0 = (l & 3) * 2;
        const size_t off = ((size_t)(n0 + 16 * w + row) * NI + i) * HI;
        #pragma unroll
        for (int gg = g0; gg < g0 + 2; ++gg){
            uint4 q = *(const uint4*)&st[row * 64 + ((gg ^ (row & 7)) << 3)];
            *(uint4*)(xcb + off + gg * 8) = q;
        }
    }
}

// ------- Kernel B: one block per (i,j); votes + fn_v (f16 MFMA) + bij -------
__global__ __launch_bounds__(256) void k_votes(
    const u16* __restrict__ xcb, const float* __restrict__ Wv,
    const float* __restrict__ Bv, const float* __restrict__ mask,
    const u16* __restrict__ fn1wh, const float* __restrict__ fn1b,
    const float* __restrict__ scoreW, const float* __restrict__ scoreb,
    u16* __restrict__ votes, u16* __restrict__ fnv, float* __restrict__ bij)
{
    __shared__ u16 vstrip[4][1024];
    __shared__ u16 fstrip[4][1024];
    const int i = blockIdx.x, j = blockIdx.y;
    const int t = threadIdx.x, w = t >> 6, l = t & 63;
    const int lr = l & 15, lg = l >> 4;
    const int isw = i & 7;

    f16x8 wb0[4], wb1[4], nb0[4], nb1[4];
    const float* wvp = Wv + (size_t)(i * NJ + j) * 4096;
    float bv[4], f1b[4], swv[4];
    #pragma unroll
    for (int ht = 0; ht < 4; ++ht){
        const int h = ht * 16 + lr;
        #pragma unroll
        for (int e = 0; e < 8; ++e){
            wb0[ht][e] = (f16)wvp[(lg * 8 + e) * 64 + h];
            wb1[ht][e] = (f16)wvp[(32 + lg * 8 + e) * 64 + h];
        }
        const u16* q = fn1wh + h * 64 + lg * 8;
        nb0[ht] = *(const f16x8*)q;
        nb1[ht] = *(const f16x8*)(q + 32);
        bv[ht]  = Bv[(size_t)(i * NJ + j) * HO + h];
        f1b[ht] = fn1b[h];
        swv[ht] = scoreW[h];
    }
    const float sb = scoreb[0];
    u16* vst = vstrip[w];
    u16* fst = fstrip[w];

    for (int nc = 0; nc < 8; ++nc){
        const int n0 = nc * 64 + 16 * w;
        const u16* ar = xcb + ((size_t)(n0 + lr) * NI + i) * HI + lg * 8;
        f16x8 a0 = *(const f16x8*)ar;
        f16x8 a1 = *(const f16x8*)(ar + 32);
        float mk[4];
        #pragma unroll
        for (int r = 0; r < 4; ++r)
            mk[r] = mask[(size_t)(n0 + lg * 4 + r) * NI + i];

        float p[4] = {};
        #pragma unroll
        for (int ht = 0; ht < 4; ++ht){
            f32x4 c4 = {};
            c4 = __builtin_amdgcn_mfma_f32_16x16x32_f16(a0, wb0[ht], c4, 0, 0, 0);
            c4 = __builtin_amdgcn_mfma_f32_16x16x32_f16(a1, wb1[ht], c4, 0, 0, 0);
            const int h = ht * 16 + lr, gp = h >> 3;
            #pragma unroll
            for (int r = 0; r < 4; ++r){
                const int rs = lg * 4 + r;
                float val = (c4[r] + bv[ht]) * mk[r];
                p[r] += val * swv[ht];
                vst[rs * 64 + ((gp ^ (rs & 7)) << 3) + (h & 7)] = f2h(val);
            }
        }
        #pragma unroll
        for (int r = 0; r < 4; ++r){
            float s = p[r];
            s += __shfl_xor(s, 1); s += __shfl_xor(s, 2);
            s += __shfl_xor(s, 4); s += __shfl_xor(s, 8);
            if (lr == 0)
                bij[((size_t)(n0 + lg * 4 + r) * NJ + j) * NI + i] = s + sb;
        }

        const u16* va = vst + lr * 64;
        f16x8 fa0 = *(const f16x8*)(va + ((lg ^ (lr & 7)) << 3));
        f16x8 fa1 = *(const f16x8*)(va + (((lg + 4) ^ (lr & 7)) << 3));
        #pragma unroll
        for (int ht = 0; ht < 4; ++ht){
            f32x4 c4 = {};
            c4 = __builtin_amdgcn_mfma_f32_16x16x32_f16(fa0, nb0[ht], c4, 0, 0, 0);
            c4 = __builtin_amdgcn_mfma_f32_16x16x32_f16(fa1, nb1[ht], c4, 0, 0, 0);
            const int h = ht * 16 + lr, gp = h >> 3;
            #pragma unroll
            for (int r = 0; r < 4; ++r){
                const int rs = lg * 4 + r;
                fst[rs * 64 + ((gp ^ (rs & 7)) << 3) + (h & 7)] = f2h(c4[r] + f1b[ht]);
            }
        }

        {
            const int row = l >> 2, g0 = (l & 3) * 2;
            const size_t off = (((size_t)(nc * 64 + 16 * w + row) * NJ + j) * NI + i) * HO;
            #pragma unroll
            for (int gg = g0; gg < g0 + 2; ++gg){
                uint4 qv = *(const uint4*)&vst[row * 64 + ((gg ^ (row & 7)) << 3)];
                *(uint4*)(votes + off + ((gg ^ isw) << 3)) = qv;
                uint4 qf = *(const uint4*)&fst[row * 64 + ((gg ^ (row & 7)) << 3)];
                *(uint4*)(fnv + off + ((gg ^ isw) << 3)) = qf;
            }
        }
    }
}

// ---------------- Kernel C: routing; ONE wave per (n,j), ZERO barriers ----------------
// Round-6 structure (proven fastest), bodies rewritten on v_dot2_f32_f16.
// NOTE: plain __launch_bounds__(256) — min-waves arg spills (round 7 lesson).
__global__ __launch_bounds__(256) void k_route(
    const u16* __restrict__ votes, const u16* __restrict__ fnv,
    const float* __restrict__ bijg, const float* __restrict__ mask,
    const float* __restrict__ alphaW, const float* __restrict__ alphab,
    const u16* __restrict__ wAh, const float* __restrict__ fe2b,
    const u16* __restrict__ wBh, const float* __restrict__ fn2b,
    const u16* __restrict__ wCth, const float* __restrict__ fe1b,
    const int* __restrict__ itersp, float* __restrict__ out)
{
    __shared__ u16 t_l[4][4096];                       // 8 KB votes tile per wave
    __shared__ float s_aij[4][64];
    __shared__ alignas(16) u16 s_vjh[4][64];           // f16 mirrors for dot2
    __shared__ alignas(16) u16 s_gh[4][64];
    __shared__ alignas(16) u16 s_wh[4][64];
    __shared__ alignas(16) u16 s_uh[4][64];

    const int t = threadIdx.x;
    const int wid = t >> 6;
    const int l = t & 63;
    const int pair = blockIdx.x * 4 + wid;
    const int n = pair >> 4, j = pair & 15;
    const size_t base = ((size_t)n * NJ + j) * (size_t)(NI * HO);

    u16*   tile = t_l[wid];
    float* aij  = s_aij[wid];
    u16*   vjh  = s_vjh[wid];
    u16*   sgh  = s_gh[wid];
    u16*   swh  = s_wh[wid];
    u16*   suh  = s_uh[wid];

    // ---- fnv -> LDS -> dr_f (row regs) ----
    uint4 dr_f[8];
    {
        const uint4* src = (const uint4*)(fnv + base);
        uint4 tb[8];
        #pragma unroll
        for (int c = 0; c < 8; ++c) tb[c] = src[c * 64 + l];
        #pragma unroll
        for (int c = 0; c < 8; ++c) *(uint4*)&tile[(c * 64 + l) * 8] = tb[c];
        #pragma unroll
        for (int c = 0; c < 8; ++c)
            dr_f[c] = *(const uint4*)&tile[l * 64 + ((c ^ (l & 7)) << 3)];
    }
    // ---- votes -> LDS (resident for nv + E row reads) ----
    {
        const uint4* src = (const uint4*)(votes + base);
        uint4 tb[8];
        #pragma unroll
        for (int c = 0; c < 8; ++c) tb[c] = src[c * 64 + l];
        #pragma unroll
        for (int c = 0; c < 8; ++c) *(uint4*)&tile[(c * 64 + l) * 8] = tb[c];
    }

    const float mki  = mask[(size_t)n * NI + l];
    const float atti = (mki == 0.f) ? -3.0e38f : 0.f;

    {   // softmax over i (in-wave)
        float s = bijg[((size_t)n * NJ + j) * NI + l] * mki + atti;
        float mx = s;
        #pragma unroll
        for (int off = 32; off; off >>= 1) mx = fmaxf(mx, __shfl_xor(mx, off));
        float pe = __expf(s - mx);
        float sm = pe;
        #pragma unroll
        for (int off = 32; off; off >>= 1) sm += __shfl_xor(sm, off);
        aij[l] = pe / sm;
    }

    const int iters = itersp[0];
    float vj = 0.f;                                // lane l owns vj[h=l]
    for (int it = 0; it < iters; ++it){
        // nv[h=l] = sum_i aij[i]*votes[i][h]  (swizzled column reads, 2 chains)
        const int gsh = (l >> 3) << 3;
        const int lo7 = l & 7;
        float ac0 = 0.f, ac1 = 0.f;
        #pragma unroll
        for (int ii = 0; ii < 32; ++ii){
            const int sw = (gsh ^ ((ii & 7) << 3)) + lo7;
            ac0 += aij[ii]      * h2f(tile[ ii       * 64 + sw]);
            ac1 += aij[ii + 32] * h2f(tile[(ii + 32) * 64 + sw]);
        }
        float nv = gelu_exact(ac0 + ac1);
        if (it == 0) vj = nv;
        else {
            float dv = nv * alphaW[l];
            #pragma unroll
            for (int off = 32; off; off >>= 1) dv += __shfl_xor(dv, off);
            float alpha = sigm(dv + alphab[0]);
            vj = alpha * nv + (1.f - alpha) * vj;
        }
        if (it == iters - 1) break;
        vjh[l] = f2h(vj);

        // g = fe2(vj), w = fn2(vj)   (fdot2; vector side from f16 mirror)
        const uint4* wa = (const uint4*)(wAh + l * 64);
        const uint4* wb = (const uint4*)(wBh + l * 64);
        float ga = 0.f, wacc = 0.f;
        #pragma unroll
        for (int c = 0; c < 8; ++c){
            uint4 vq = *(const uint4*)&vjh[c * 8];
            ga   = dot8h(wa[c], vq, ga);
            wacc = dot8h(wb[c], vq, wacc);
        }
        float g = ga + fe2b[l];
        sgh[l] = f2h(g);
        swh[l] = f2h(wacc + fn2b[l]);

        // u = fe1W^T g ; cv = fe1b . g
        const uint4* wc = (const uint4*)(wCth + l * 64);
        float ua = 0.f;
        #pragma unroll
        for (int c = 0; c < 8; ++c){
            uint4 gq = *(const uint4*)&sgh[c * 8];
            ua = dot8h(wc[c], gq, ua);
        }
        suh[l] = f2h(ua);
        float cv = fe1b[l] * g;
        #pragma unroll
        for (int off = 32; off; off >>= 1) cv += __shfl_xor(cv, off);

        // M[i=l] = -sum_h |fnv[i][h] - w[h]|   (packed f16 sub/abs/add)
        f16x2 macc = {(f16)0.f, (f16)0.f};
        #pragma unroll
        for (int c = 0; c < 8; ++c){
            uint4 q = dr_f[c];
            uint4 wq = *(const uint4*)&swh[c * 8];
            macc += habs2(bch2(q.x) - bch2(wq.x));
            macc += habs2(bch2(q.y) - bch2(wq.y));
            macc += habs2(bch2(q.z) - bch2(wq.z));
            macc += habs2(bch2(q.w) - bch2(wq.w));
        }
        float Mreg = -((float)macc[0] + (float)macc[1]);

        // E[i=l] = votes[i].u + cv   (row reads from LDS, fdot2)
        float e0 = 0.f, e1 = 0.f;
        #pragma unroll
        for (int c = 0; c < 4; ++c){
            uint4 q  = *(const uint4*)&tile[l * 64 + ((c ^ (l & 7)) << 3)];
            uint4 q2 = *(const uint4*)&tile[l * 64 + (((c + 4) ^ (l & 7)) << 3)];
            e0 = dot8h(q,  *(const uint4*)&suh[c * 8], e0);
            e1 = dot8h(q2, *(const uint4*)&suh[(c + 4) * 8], e1);
        }
        aij[l] = tanhf(cv + e0 + e1) * sigm(Mreg * mki + atti);
    }

    out[((size_t)n * NJ + j) * HO + l] = vj;
}

extern "C" void kernel_launch(void* const* d_in, const int* in_sizes, int n_in,
                              void* d_out, int out_size, void* d_ws, size_t ws_size,
                              hipStream_t stream)
{
    (void)in_sizes; (void)n_in; (void)out_size; (void)ws_size;
    const float* x      = (const float*)d_in[0];
    const float* mask   = (const float*)d_in[1];
    const float* Wcap   = (const float*)d_in[2];
    const float* Bcap   = (const float*)d_in[3];
    const float* Wv     = (const float*)d_in[4];
    const float* Bv     = (const float*)d_in[5];
    const float* scoreW = (const float*)d_in[6];
    const float* scoreb = (const float*)d_in[7];
    const float* alphaW = (const float*)d_in[8];
    const float* alphab = (const float*)d_in[9];
    const float* fe1W   = (const float*)d_in[10];
    const float* fe1b   = (const float*)d_in[11];
    const float* fe2W   = (const float*)d_in[12];
    const float* fe2b   = (const float*)d_in[13];
    const float* fn1W   = (const float*)d_in[14];
    const float* fn1b   = (const float*)d_in[15];
    const float* fn2W   = (const float*)d_in[16];
    const float* fn2b   = (const float*)d_in[17];
    const int*   itersp = (const int*)d_in[18];
    float* out = (float*)d_out;

    char* ws = (char*)d_ws;
    u16*   xcb   = (u16*)ws;                      //   4,194,304 B
    u16*   vts   = (u16*)(ws + 4194304);          //  67,108,864 B
    u16*   fnvp  = (u16*)(ws + 71303168);         //  67,108,864 B
    float* bij   = (float*)(ws + 138412032);      //   2,097,152 B
    u16*   fn1wh = (u16*)(ws + 140509184);        //       8,192 B
    u16*   wAh   = (u16*)(ws + 140517376);        //       8,192 B
    u16*   wBh   = (u16*)(ws + 140525568);        //       8,192 B
    u16*   wCth  = (u16*)(ws + 140533760);        //       8,192 B  (~140.5 MB)

    k_prep_small<<<1, 256, 0, stream>>>(fn1W, fe2W, fn2W, fe1W, fn1wh, wAh, wBh, wCth);
    k_xc        <<<dim3(8, 64), 256, 0, stream>>>(x, Wcap, Bcap, xcb);
    k_votes     <<<dim3(64, 16), 256, 0, stream>>>(xcb, Wv, Bv, mask, fn1wh, fn1b,
                                                   scoreW, scoreb, vts, fnvp, bij);
    k_route     <<<2048, 256, 0, stream>>>(vts, fnvp, bij, mask, alphaW, alphab,
                                           wAh, fe2b, wBh, fn2b, wCth, fe1b,
                                           itersp, out);
}